// Round 15
// baseline (106.420 us; speedup 1.0000x reference)
//
#include <hip/hip_runtime.h>
#include <hip/hip_bf16.h>

#define B_SZ 4096
#define F_CAT 26
#define NUM_N 13
#define ED 64
#define D_DIM 1728   // 27*64
#define E_EXP 8
#define T_TASK 2
#define BOT0 512
#define BOT1 256
#define TOW0 128
#define TOW1 64

typedef __bf16 bf16x8 __attribute__((ext_vector_type(8)));
typedef float f32x4 __attribute__((ext_vector_type(4)));
typedef float f32x16 __attribute__((ext_vector_type(16)));
typedef long lx2 __attribute__((ext_vector_type(2)));
typedef int i32x4 __attribute__((ext_vector_type(4)));
typedef int i32x8 __attribute__((ext_vector_type(8)));

#define SCL 0x7F7F7F7F  // E8M0 1.0 in all 4 bytes

__device__ __forceinline__ void gload_lds16(const void* g, void* l) {
  __builtin_amdgcn_global_load_lds(
      (const __attribute__((address_space(1))) void*)g,
      (__attribute__((address_space(3))) void*)l, 16, 0, 0);
}

#define BAR() do { asm volatile("" ::: "memory"); __builtin_amdgcn_s_barrier(); asm volatile("" ::: "memory"); } while (0)
#define VM4() asm volatile("s_waitcnt vmcnt(4)" ::: "memory")
#define VM3() asm volatile("s_waitcnt vmcnt(3)" ::: "memory")

// old k-perm (16x16 frag layout) — used for WgT8 (gate B operand)
__device__ __forceinline__ int permk(int k6) {
  return (k6 & 7) + (((k6 >> 3) & 3) << 4) + (((k6 >> 5) & 1) << 3);
}

// MX content layout (64-row regions): element (row, k_abs) -> byte position.
// Proven on HW rounds 11/12/14.
__device__ __forceinline__ size_t mxpos(int row, int kabs, int K) {
  int kt = kabs >> 6, kk = kabs & 63;
  int reg = row & ~63, ro = row & 63;
  int sub = ro >> 5, rr = ro & 31, r = rr & 15;
  int u = ((kk >> 5) << 1) | ((rr >> 4) & 1);
  int p = (kk >> 4) & 1;
  int g = (sub << 1) | p;
  return (size_t)(reg + g * 16 + r) * K + kt * 64 + u * 16 + (kk & 15);
}

// ---------------- f32 -> OCP e4m3fn: software fallback (RNE, saturating)
__device__ __forceinline__ unsigned char f2e4m3_sw(float x) {
  unsigned su = (__float_as_uint(x) >> 24) & 0x80u;
  float ax = fabsf(x);
  if (!(ax < 448.f)) return (unsigned char)(su | 0x7E);
  if (ax == 0.f) return (unsigned char)su;
  int e;
  float m = frexpf(ax, &e);
  int E = e - 1;
  if (E < -6) {
    int mi = (int)rintf(ldexpf(ax, 9));
    if (mi >= 8) return (unsigned char)(su | 0x08);
    return (unsigned char)(su | mi);
  }
  int mi = (int)rintf(ldexpf(m, 4));
  if (mi == 16) { mi = 8; E += 1; if (E > 8) return (unsigned char)(su | 0x7E); }
  return (unsigned char)(su | ((E + 7) << 3) | (mi - 8));
}

// HW packed convert (gfx950: OCP e4m3); hi-select must be a LITERAL.
#if __has_builtin(__builtin_amdgcn_cvt_pk_fp8_f32)
#define HAS_HW_FP8 1
__device__ __forceinline__ int cvtpk8_lo(float a, float b, int old) {
  return __builtin_amdgcn_cvt_pk_fp8_f32(a, b, old, false);
}
__device__ __forceinline__ int cvtpk8_hi(float a, float b, int old) {
  return __builtin_amdgcn_cvt_pk_fp8_f32(a, b, old, true);
}
__device__ __forceinline__ unsigned char f2e4m3(float x) {
  return (unsigned char)(__builtin_amdgcn_cvt_pk_fp8_f32(x, x, 0, false) & 0xFF);
}
#else
#define HAS_HW_FP8 0
__device__ __forceinline__ unsigned char f2e4m3(float x) { return f2e4m3_sw(x); }
#endif

// pack 4 floats -> 4 fp8 bytes (1 u32)
__device__ __forceinline__ unsigned pk4_fp8(float a, float b, float c, float d) {
#if HAS_HW_FP8
  int v = cvtpk8_lo(a, b, 0);
  v = cvtpk8_hi(c, d, v);
  return (unsigned)v;
#else
  return (unsigned)f2e4m3_sw(a) | ((unsigned)f2e4m3_sw(b) << 8) |
         ((unsigned)f2e4m3_sw(c) << 16) | ((unsigned)f2e4m3_sw(d) << 24);
#endif
}

// e4m3 -> f32 decode (exact; fea can't be NaN: relu output, sat-encoded)
__device__ __forceinline__ float dec8(unsigned char v) {
  int e = (v >> 3) & 15, m = v & 7;
  float mag = e ? __int_as_float(((e + 120) << 23) | (m << 20))
                : (float)m * 0.001953125f;  // 2^-9 subnormal step
  return (v & 0x80) ? -mag : mag;
}

// =========================================================================
// prep_all: weight transposes (We1/We2 -> fp8x16 MX, Wg -> fp8x16 k-perm)
// PLUS the embedding gather/numeric linear (fp8x16 MX), merged into one
// dispatch. Blocks: [0,6912) We1, [6912,7936) We2, [7936,8044) Wg,
// [8044, 8044+1728) embed.
// =========================================================================
__device__ __forceinline__ void trans_tile_fp8mx(
    const float* __restrict__ inp, unsigned char* __restrict__ outp,
    int R, int C, int cx, int ry, float (*tile)[33])
{
  int c0 = cx * 32, r0 = ry * 32;
  int tx = threadIdx.x & 31, ty = threadIdx.x >> 5;
#pragma unroll
  for (int i = 0; i < 32; i += 8)
    tile[ty + i][tx] = inp[(size_t)(r0 + ty + i) * C + c0 + tx];
  __syncthreads();
  int ki = r0 + tx;
#pragma unroll
  for (int i = 0; i < 32; i += 8)
    outp[mxpos(c0 + ty + i, ki, R)] = f2e4m3(tile[tx][ty + i] * 16.f);
}

__global__ __launch_bounds__(256) void prep_all(
    const float* __restrict__ We1, const float* __restrict__ We2,
    const float* __restrict__ Wg,
    const int* __restrict__ cat, const float* __restrict__ numx,
    const int* __restrict__ offsets, const float* __restrict__ W_emb,
    const float* __restrict__ Wn, const float* __restrict__ bnum,
    unsigned char* __restrict__ We1T8, unsigned char* __restrict__ We2T8,
    unsigned char* __restrict__ WgT8, unsigned char* __restrict__ emb8)
{
  __shared__ float tile[32][33];
  int id = blockIdx.x;
  if (id < 6912) {
    int z = id / 864, r = id - z * 864;
    int cx = r & 15, ry = r >> 4;
    trans_tile_fp8mx(We1 + (size_t)z * D_DIM * BOT0, We1T8 + (size_t)z * D_DIM * BOT0,
                     D_DIM, BOT0, cx, ry, tile);
  } else if (id < 7936) {
    int r2 = id - 6912;
    int z = r2 >> 7, r = r2 & 127;
    int cx = r & 7, ry = r >> 3;
    trans_tile_fp8mx(We2 + (size_t)z * BOT0 * BOT1, We2T8 + (size_t)z * BOT0 * BOT1,
                     BOT0, BOT1, cx, ry, tile);
  } else if (id < 8044) {
    int i = (id - 7936) * 256 + threadIdx.x; // over 16*1728
    int n = i / D_DIM, d = i - n * D_DIM;
    int t = n >> 3, e2 = n & 7;
    int pd = (d & ~63) + permk(d & 63);
    WgT8[(size_t)n * D_DIM + pd] =
        f2e4m3(Wg[((size_t)t * D_DIM + d) * E_EXP + e2] * 16.f);
  } else {
    // embedding gather + numeric linear -> emb8 (fp8 x16, MX layout)
    int W = (id - 8044) * 256 + threadIdx.x;
    int prow = W / 108, ucol = W - prow * 108;
    int f = ucol >> 2, u = ucol & 3;
    int reg = prow & ~63, po = prow & 63;
    int g = po >> 4, r = po & 15;
    int sub = g >> 1, p = g & 1;
    int h = u >> 1, rbit = u & 1;
    int b = reg + sub * 32 + rbit * 16 + r;
    int kk = h * 32 + p * 16;
    float vals[16];
    if (f < F_CAT) {
      int row = cat[(size_t)b * F_CAT + f] + offsets[f];
      const float4* src = reinterpret_cast<const float4*>(&W_emb[(size_t)row * ED + kk]);
#pragma unroll
      for (int q = 0; q < 4; ++q) {
        float4 v = src[q];
        vals[q * 4 + 0] = v.x; vals[q * 4 + 1] = v.y;
        vals[q * 4 + 2] = v.z; vals[q * 4 + 3] = v.w;
      }
    } else {
#pragma unroll
      for (int j = 0; j < 16; ++j) vals[j] = bnum[kk + j];
      for (int n = 0; n < NUM_N; ++n) {
        float x = numx[(size_t)b * NUM_N + n];
        const float* wr = &Wn[n * ED + kk];
#pragma unroll
        for (int j = 0; j < 16; ++j) vals[j] = fmaf(x, wr[j], vals[j]);
      }
    }
    uint4 o;
    o.x = pk4_fp8(vals[0] * 16.f, vals[1] * 16.f, vals[2] * 16.f, vals[3] * 16.f);
    o.y = pk4_fp8(vals[4] * 16.f, vals[5] * 16.f, vals[6] * 16.f, vals[7] * 16.f);
    o.z = pk4_fp8(vals[8] * 16.f, vals[9] * 16.f, vals[10] * 16.f, vals[11] * 16.f);
    o.w = pk4_fp8(vals[12] * 16.f, vals[13] * 16.f, vals[14] * 16.f, vals[15] * 16.f);
    *reinterpret_cast<uint4*>(&emb8[(size_t)prow * D_DIM + f * 64 + u * 16]) = o;
  }
}

// ---------------- gate GEMM (fp8, M=4096,N=16,K=1728) + fused softmax
__global__ __launch_bounds__(256) void gate_mfma(
    const unsigned char* __restrict__ emb8, const unsigned char* __restrict__ WgT8,
    const float* __restrict__ bg, float* __restrict__ gate)
{
  int wid = threadIdx.x >> 6, lane = threadIdx.x & 63;
  int l15 = lane & 15, lh = lane >> 4;
  int r0 = (blockIdx.x * 4 + wid) * 16;
  f32x4 acc = {};
  int b = r0 + l15;
  int reg = b & ~63, ro = b & 63;
  int sub = ro >> 5, rr = ro & 31;
  int rbit = (rr >> 4) & 1, rq = rr & 15;
  int pgh = lh >> 1;
  int prow = reg + (((sub << 1) | pgh) << 4) + rq;
  const unsigned char* arow = emb8 + (size_t)prow * D_DIM + rbit * 16 + (lh & 1) * 8;
  const unsigned char* brow = WgT8 + (size_t)l15 * D_DIM + lh * 16;
#pragma unroll 3
  for (int k = 0; k < D_DIM; k += 64) {
    long a0 = *reinterpret_cast<const long*>(arow + k);
    long a1 = *reinterpret_cast<const long*>(arow + k + 32);
    lx2 bv = *reinterpret_cast<const lx2*>(brow + k);
    acc = __builtin_amdgcn_mfma_f32_16x16x32_fp8_fp8(a0, bv[0], acc, 0, 0, 0);
    acc = __builtin_amdgcn_mfma_f32_16x16x32_fp8_fp8(a1, bv[1], acc, 0, 0, 0);
  }
  int t = l15 >> 3, e = l15 & 7;
  float bv = bg[t * E_EXP + e];
#pragma unroll
  for (int r = 0; r < 4; ++r) {
    float lg = acc[r] * (1.f / 256.f) + bv;
    float m = lg;
    m = fmaxf(m, __shfl_xor(m, 1));
    m = fmaxf(m, __shfl_xor(m, 2));
    m = fmaxf(m, __shfl_xor(m, 4));
    float ex = expf(lg - m);
    float s = ex;
    s += __shfl_xor(s, 1);
    s += __shfl_xor(s, 2);
    s += __shfl_xor(s, 4);
    int row = r0 + lh * 4 + r;
    gate[((size_t)t * B_SZ + row) * E_EXP + e] = ex / s;
  }
}

// load a 32-B fragment (two b128 at +1024 = pieces p0,p1) into v8i32
__device__ __forceinline__ i32x8 ld32(const char* base, int off) {
  i32x4 a = *reinterpret_cast<const i32x4*>(base + off);
  i32x4 b = *reinterpret_cast<const i32x4*>(base + off + 1024);
  i32x8 r;
  r[0] = a[0]; r[1] = a[1]; r[2] = a[2]; r[3] = a[3];
  r[4] = b[0]; r[5] = b[1]; r[6] = b[2]; r[7] = b[3];
  return r;
}

#define MXMFMA(va, vb, c) \
  __builtin_amdgcn_mfma_scale_f32_32x32x64_f8f6f4(va, vb, c, 0, 0, 0, SCL, 0, SCL)

// =========================================================================
// MX-fp8 2-phase 256x256 BK=64 GEMM (GEMM1) — proven (rounds 11-14).
// H written as fp8 x16 MX layout via HW cvt_pk. Loop LDS 96 KB, cs8 64 KB.
// =========================================================================
__global__ __launch_bounds__(512, 2) void gemm_mx(
    const unsigned char* __restrict__ A8, size_t strideAe,
    const unsigned char* __restrict__ BT8,
    const float* __restrict__ bias,
    unsigned char* __restrict__ C8,
    int M, int N, int K)
{
  extern __shared__ char smem[];
  int e = blockIdx.z;
  const unsigned char* Ap = A8 + strideAe * (size_t)e;
  const unsigned char* Bp = BT8 + (size_t)e * N * K;
  const float* bp = bias + (size_t)e * N;
  unsigned char* Cp8 = C8 + (size_t)e * M * N;
  int bm0 = blockIdx.x * 256, bn0 = blockIdx.y * 256;

  int tid = threadIdx.x;
  int wid = tid >> 6, lane = tid & 63;
  int l15 = lane & 15, lh = lane >> 4;
  int l31 = lane & 31, hl = lane >> 5;
  int wrow = (wid >> 2) * 128, wcol = (wid & 3) * 64;

  int slotc = (lh ^ (((l15 >> 3) & 1) << 1)) << 4;
  const char* rdA = smem + (wrow + l15) * 64 + slotc;
  const char* rdB = smem + 49152 + (wcol + l15) * 64 + slotc;
  char* stA = smem + (wid << 10);
  char* stB = smem + 49152 + (wid << 10);

  int srow = tid >> 2;
  int ssw = (tid & 3) ^ (((srow >> 3) & 1) << 1);
  const unsigned char* gA0 = Ap + (size_t)(bm0 + srow) * K + ssw * 16;
  const unsigned char* gA1 = Ap + (size_t)(bm0 + 128 + srow) * K + ssw * 16;
  const unsigned char* gB0 = Bp + (size_t)(bn0 + srow) * K + ssw * 16;
  const unsigned char* gB1 = Bp + (size_t)(bn0 + 128 + srow) * K + ssw * 16;

  auto STAGE = [&](int koff, int buf) {
    gload_lds16(gA0 + koff, stA + buf * 16384);
    gload_lds16(gA1 + koff, stA + buf * 16384 + 8192);
    gload_lds16(gB0 + koff, stB + buf * 16384);
    gload_lds16(gB1 + koff, stB + buf * 16384 + 8192);
  };

  f32x16 acc[4][2] = {};
  int NT = K >> 6;

  STAGE(0, 0);
  STAGE(64, 1);
  VM4();
  BAR();

  int bufc = 0, koff = 128;
  for (int T = 0; T < NT; ++T) {
    const char* As = rdA + bufc * 16384;
    const char* Bs = rdB + bufc * 16384;
    int sb = bufc >= 1 ? bufc - 1 : 2;
    i32x8 va0, va1, vb0, vb1;

    // ---- p0: frags mi0,mi1 + both B chunks; stage tile T+2
    va0 = ld32(As, 0);
    va1 = ld32(As, 2048);
    vb0 = ld32(Bs, 0);
    vb1 = ld32(Bs, 2048);
    STAGE(koff, sb);
    BAR();
    __builtin_amdgcn_s_setprio(1);
    acc[0][0] = MXMFMA(va0, vb0, acc[0][0]);
    acc[0][1] = MXMFMA(va0, vb1, acc[0][1]);
    acc[1][0] = MXMFMA(va1, vb0, acc[1][0]);
    acc[1][1] = MXMFMA(va1, vb1, acc[1][1]);
    __builtin_amdgcn_s_setprio(0);
    BAR();

    // ---- p1: frags mi2,mi3; VM4 certifies T+1
    va0 = ld32(As, 4096);
    va1 = ld32(As, 4096 + 2048);
    BAR();
    __builtin_amdgcn_s_setprio(1);
    acc[2][0] = MXMFMA(va0, vb0, acc[2][0]);
    acc[2][1] = MXMFMA(va0, vb1, acc[2][1]);
    acc[3][0] = MXMFMA(va1, vb0, acc[3][0]);
    acc[3][1] = MXMFMA(va1, vb1, acc[3][1]);
    __builtin_amdgcn_s_setprio(0);
    VM4();
    BAR();

    koff += 64;
    bufc = bufc == 2 ? 0 : bufc + 1;
  }

  // epilogue: drain; scale 1/256 + bias + relu; fp8 x16 MX layout via HW
  // cvt_pk into cs8 [256][256], then coalesced 16 B stores.
  asm volatile("s_waitcnt vmcnt(0)" ::: "memory");
  BAR();
  unsigned char* cs8 = (unsigned char*)smem;
#pragma unroll
  for (int mi = 0; mi < 4; ++mi) {
#pragma unroll
    for (int nj = 0; nj < 2; ++nj) {
      int colT = wcol + nj * 32 + l31;       // k index within tile (0..255)
      float bv = bp[bn0 + colT];
      int kk = colT & 63;
      int ktrel = colT >> 6;
      int p = (kk >> 4) & 1;
      int ubase = (kk >> 5) << 1;
      int b4 = kk & 15;
      f32x16 a = acc[mi][nj];
      int rowBase = wrow + mi * 32 + (hl << 2);
#pragma unroll
      for (int rg = 0; rg < 16; rg += 2) {
        int row0 = rowBase + (rg & 3) + ((rg >> 2) << 3);
        float v0 = fmaxf(a[rg] * (1.f / 256.f) + bv, 0.f) * 16.f;
        float v1 = fmaxf(a[rg + 1] * (1.f / 256.f) + bv, 0.f) * 16.f;
#if HAS_HW_FP8
        int pk = cvtpk8_lo(v0, v1, 0);
#else
        int pk = (int)f2e4m3_sw(v0) | ((int)f2e4m3_sw(v1) << 8);
#endif
#pragma unroll
        for (int q = 0; q < 2; ++q) {
          int rowT = row0 + q;
          int regrel = rowT & ~63, ro = rowT & 63;
          int sub = ro >> 5, rr2 = ro & 31, r = rr2 & 15;
          int u = ubase | ((rr2 >> 4) & 1);
          int g = (sub << 1) | p;
          cs8[(regrel + g * 16 + r) * 256 + ktrel * 64 + u * 16 + b4] =
              (unsigned char)((pk >> (q * 8)) & 0xFF);
        }
      }
    }
  }
  BAR();
  {
    int rr = tid >> 4, c16 = (tid & 15) * 16; // 32 rows/pass
#pragma unroll
    for (int p2 = 0; p2 < 8; ++p2) {
      int row = p2 * 32 + rr;
      *reinterpret_cast<uint4*>(&Cp8[(size_t)(bm0 + row) * N + bn0 + c16]) =
          *reinterpret_cast<const uint4*>(&cs8[(size_t)row * 256 + c16]);
    }
  }
}

// =========================================================================
// MX-fp8 BM=128 x BN=256 GEMM (GEMM2) — proven schedule; round-15 change:
// fea emitted as fp8 x16 (plain row-major) via HW cvt_pk. cs8 = 32 KB.
// =========================================================================
__global__ __launch_bounds__(512, 2) void gemm_mx128(
    const unsigned char* __restrict__ A8, size_t strideAe,
    const unsigned char* __restrict__ BT8,
    const float* __restrict__ bias,
    unsigned char* __restrict__ C8,
    int M, int N, int K)
{
  extern __shared__ char smem[];
  int e = blockIdx.z;
  const unsigned char* Ap = A8 + strideAe * (size_t)e;
  const unsigned char* Bp = BT8 + (size_t)e * N * K;
  const float* bp = bias + (size_t)e * N;
  unsigned char* Cp8 = C8 + (size_t)e * M * N;
  int bm0 = blockIdx.x * 128;

  int tid = threadIdx.x;
  int wid = tid >> 6, lane = tid & 63;
  int l15 = lane & 15, lh = lane >> 4;
  int l31 = lane & 31, hl = lane >> 5;
  int wrow = (wid >> 2) * 64, wcol = (wid & 3) * 64;

  int slotc = (lh ^ (((l15 >> 3) & 1) << 1)) << 4;
  const char* rdA = smem + (wrow + l15) * 64 + slotc;
  const char* rdB = smem + 24576 + (wcol + l15) * 64 + slotc;
  char* stA = smem + (wid << 10);
  char* stB = smem + 24576 + (wid << 10);

  int srow = tid >> 2;
  int ssw = (tid & 3) ^ (((srow >> 3) & 1) << 1);
  const unsigned char* gA0 = Ap + (size_t)(bm0 + srow) * K + ssw * 16;
  const unsigned char* gB0 = Bp + (size_t)srow * K + ssw * 16;
  const unsigned char* gB1 = Bp + (size_t)(128 + srow) * K + ssw * 16;

  auto STAGE = [&](int koff, int buf) {
    gload_lds16(gA0 + koff, stA + buf * 8192);
    gload_lds16(gB0 + koff, stB + buf * 16384);
    gload_lds16(gB1 + koff, stB + buf * 16384 + 8192);
  };

  f32x16 acc[2][2] = {};
  int NT = K >> 6;  // 8

  STAGE(0, 0);
  STAGE(64, 1);
  VM3();
  BAR();

  int bufc = 0, koff = 128;
  for (int T = 0; T < NT; ++T) {
    const char* As = rdA + bufc * 8192;
    const char* Bs = rdB + bufc * 16384;
    int sb = bufc >= 1 ? bufc - 1 : 2;
    i32x8 va, vb0, vb1;

    // ---- p0: mi0 + both B chunks; stage tile T+2
    va = ld32(As, 0);
    vb0 = ld32(Bs, 0);
    vb1 = ld32(Bs, 2048);
    STAGE(koff, sb);
    BAR();
    __builtin_amdgcn_s_setprio(1);
    acc[0][0] = MXMFMA(va, vb0, acc[0][0]);
    acc[0][1] = MXMFMA(va, vb1, acc[0][1]);
    __builtin_amdgcn_s_setprio(0);
    BAR();

    // ---- p1: mi1; VM3 certifies T+1
    va = ld32(As, 2048);
    BAR();
    __builtin_amdgcn_s_setprio(1);
    acc[1][0] = MXMFMA(va, vb0, acc[1][0]);
    acc[1][1] = MXMFMA(va, vb1, acc[1][1]);
    __builtin_amdgcn_s_setprio(0);
    VM3();
    BAR();

    koff += 64;
    bufc = bufc == 2 ? 0 : bufc + 1;
  }

  // epilogue: fea fp8 x16 via cs8 [128][256] (32 KB), coalesced 16 B/lane
  asm volatile("s_waitcnt vmcnt(0)" ::: "memory");
  BAR();
  unsigned char* cs8 = (unsigned char*)smem;
#pragma unroll
  for (int mi = 0; mi < 2; ++mi) {
#pragma unroll
    for (int nj = 0; nj < 2; ++nj) {
      int colT = wcol + nj * 32 + l31;
      float bv = bp[colT];
      f32x16 a = acc[mi][nj];
      int rowBase = wrow + mi * 32 + (hl << 2);
#pragma unroll
      for (int rg = 0; rg < 16; rg += 2) {
        int row0 = rowBase + (rg & 3) + ((rg >> 2) << 3);
        float v0 = fmaxf(a[rg] * (1.f / 256.f) + bv, 0.f) * 16.f;
        float v1 = fmaxf(a[rg + 1] * (1.f / 256.f) + bv, 0.f) * 16.f;
#if HAS_HW_FP8
        int pk = cvtpk8_lo(v0, v1, 0);
#else
        int pk = (int)f2e4m3_sw(v0) | ((int)f2e4m3_sw(v1) << 8);
#endif
        cs8[(size_t)row0 * 256 + colT] = (unsigned char)(pk & 0xFF);
        cs8[(size_t)(row0 + 1) * 256 + colT] = (unsigned char)((pk >> 8) & 0xFF);
      }
    }
  }
  BAR();
  {
    int rr = tid >> 4, c16 = (tid & 15) * 16;  // 32 rows/pass, 4 passes
#pragma unroll
    for (int p2 = 0; p2 < 4; ++p2) {
      int row = p2 * 32 + rr;
      *reinterpret_cast<uint4*>(&Cp8[(size_t)(bm0 + row) * N + c16]) =
          *reinterpret_cast<const uint4*>(&cs8[(size_t)row * 256 + c16]);
    }
  }
}

// ---------------- gate-combine + tower MLPs + sigmoid
// Round 15: fea is fp8 x16; gate prescaled by 1/16 on load; dec8 decode.
#define TB 16
__global__ __launch_bounds__(256) void combine_tower(
    const float* __restrict__ gate, const unsigned char* __restrict__ fea8,
    const float* __restrict__ Wt1, const float* __restrict__ bt1,
    const float* __restrict__ Wt2, const float* __restrict__ bt2,
    const float* __restrict__ Wt3, const float* __restrict__ bt3,
    float* __restrict__ out)
{
  int t = blockIdx.y;
  int b0 = blockIdx.x * TB;
  int tid = threadIdx.x;
  __shared__ float gs[TB][E_EXP];
  __shared__ float tf[TB][BOT1];
  __shared__ float h1[TB][TOW0];
  __shared__ float h2[TB][TOW1];
  if (tid < TB * E_EXP) {
    int bl = tid >> 3, e = tid & 7;
    gs[bl][e] = gate[((size_t)t * B_SZ + b0 + bl) * E_EXP + e] * (1.f / 16.f);
  }
  __syncthreads();
  for (int i = tid; i < TB * BOT1; i += 256) {
    int bl = i >> 8, o = i & 255;
    float s = 0.f;
#pragma unroll
    for (int e = 0; e < E_EXP; ++e)
      s = fmaf(gs[bl][e],
               dec8(fea8[((size_t)e * B_SZ + b0 + bl) * BOT1 + o]), s);
    tf[bl][o] = s;
  }
  __syncthreads();
  {
    int h = tid & 127, half = tid >> 7;
    float a[8] = {0, 0, 0, 0, 0, 0, 0, 0};
    for (int d = 0; d < BOT1; ++d) {
      float w = Wt1[((size_t)t * BOT1 + d) * TOW0 + h];
#pragma unroll
      for (int q = 0; q < 8; ++q) a[q] = fmaf(w, tf[half * 8 + q][d], a[q]);
    }
    float bv = bt1[t * TOW0 + h];
#pragma unroll
    for (int q = 0; q < 8; ++q) h1[half * 8 + q][h] = fmaxf(a[q] + bv, 0.f);
  }
  __syncthreads();
  {
    int h = tid & 63, qt = tid >> 6;
    float a[4] = {0, 0, 0, 0};
    for (int d = 0; d < TOW0; ++d) {
      float w = Wt2[((size_t)t * TOW0 + d) * TOW1 + h];
#pragma unroll
      for (int q = 0; q < 4; ++q) a[q] = fmaf(w, h1[qt * 4 + q][d], a[q]);
    }
    float bv = bt2[t * TOW1 + h];
#pragma unroll
    for (int q = 0; q < 4; ++q) h2[qt * 4 + q][h] = fmaxf(a[q] + bv, 0.f);
  }
  __syncthreads();
  {
    int l16 = tid & 15, bl = tid >> 4;
    float p = 0.f;
#pragma unroll
    for (int d = l16; d < TOW1; d += 16) p = fmaf(h2[bl][d], Wt3[t * TOW1 + d], p);
#pragma unroll
    for (int o = 8; o; o >>= 1) p += __shfl_down(p, o, 16);
    if (l16 == 0) {
      float lg = p + bt3[t];
      out[(size_t)t * B_SZ + b0 + bl] = 1.f / (1.f + expf(-lg));
    }
  }
}

extern "C" void kernel_launch(void* const* d_in, const int* in_sizes, int n_in,
                              void* d_out, int out_size, void* d_ws, size_t ws_size,
                              hipStream_t stream) {
  const int* cat = (const int*)d_in[0];
  const float* numx = (const float*)d_in[1];
  const int* offsets = (const int*)d_in[2];
  const float* W_emb = (const float*)d_in[3];
  const float* Wn = (const float*)d_in[4];
  const float* bnv = (const float*)d_in[5];
  const float* We1 = (const float*)d_in[6];
  const float* be1 = (const float*)d_in[7];
  const float* We2 = (const float*)d_in[8];
  const float* be2 = (const float*)d_in[9];
  const float* Wg = (const float*)d_in[10];
  const float* bg = (const float*)d_in[11];
  const float* Wt1 = (const float*)d_in[12];
  const float* bt1 = (const float*)d_in[13];
  const float* Wt2 = (const float*)d_in[14];
  const float* bt2 = (const float*)d_in[15];
  const float* Wt3 = (const float*)d_in[16];
  const float* bt3 = (const float*)d_in[17];
  float* out = (float*)d_out;

  char* ws = (char*)d_ws;
  size_t off = 0;
  auto alloc = [&](size_t bytes) {
    char* p = ws + off;
    off += (bytes + 255) & ~(size_t)255;
    return p;
  };
  unsigned char*  emb8  = (unsigned char*)alloc((size_t)B_SZ * D_DIM);
  unsigned char*  We1T8 = (unsigned char*)alloc((size_t)E_EXP * BOT0 * D_DIM);
  unsigned char*  We2T8 = (unsigned char*)alloc((size_t)E_EXP * BOT1 * BOT0);
  unsigned char*  H8    = (unsigned char*)alloc((size_t)E_EXP * B_SZ * BOT0);
  unsigned char*  fea8  = (unsigned char*)alloc((size_t)E_EXP * B_SZ * BOT1);
  float* gate = (float*)alloc((size_t)T_TASK * B_SZ * E_EXP * 4);
  unsigned char*  WgT8  = (unsigned char*)alloc((size_t)T_TASK * E_EXP * D_DIM);
  (void)alloc(4096); // slack: gemm tail prefetch reads overrun up to ~640 B

  hipFuncSetAttribute((const void*)gemm_mx,
                      hipFuncAttributeMaxDynamicSharedMemorySize, 98304);
  hipFuncSetAttribute((const void*)gemm_mx128,
                      hipFuncAttributeMaxDynamicSharedMemorySize, 73728);

  // 1. merged weight prep + embedding (We1T8/We2T8 MX, WgT8 k-perm, emb8 MX)
  prep_all<<<dim3(8044 + B_SZ * 108 / 256), 256, 0, stream>>>(
      We1, We2, Wg, cat, numx, offsets, W_emb, Wn, bnv,
      We1T8, We2T8, WgT8, emb8);

  // 2. gate GEMM (fp8 direct-from-global) + softmax
  gate_mfma<<<dim3(B_SZ / 64), 256, 0, stream>>>(emb8, WgT8, bg, gate);

  // 3. expert layer 1 (MX-fp8): (4096x1728)x(1728x512) x8 -> H8 fp8-MX
  gemm_mx<<<dim3(B_SZ / 256, BOT0 / 256, E_EXP), 512, 98304, stream>>>(
      emb8, (size_t)0, We1T8, be1, H8, B_SZ, BOT0, D_DIM);

  // 4. expert layer 2 (MX-fp8): (4096x512)x(512x256) x8 -> fea8 fp8 [256 blocks]
  gemm_mx128<<<dim3(B_SZ / 128, 1, E_EXP), 512, 73728, stream>>>(
      H8, (size_t)B_SZ * BOT0, We2T8, be2, fea8, B_SZ, BOT1, BOT0);

  // 5. gated combine + towers + sigmoid (fp8 fea, dec8 decode)
  combine_tower<<<dim3(B_SZ / TB, T_TASK), 256, 0, stream>>>(
      gate, fea8, Wt1, bt1, Wt2, bt2, Wt3, bt3, out);
}

// Round 16
// 100.989 us; speedup vs baseline: 1.0538x; 1.0538x over previous
//
#include <hip/hip_runtime.h>
#include <hip/hip_bf16.h>

#define B_SZ 4096
#define F_CAT 26
#define NUM_N 13
#define ED 64
#define D_DIM 1728   // 27*64 = 13*128 + 64
#define KS4 896      // fp4 row stride bytes = 14 * 64
#define E_EXP 8
#define T_TASK 2
#define BOT0 512
#define BOT1 256
#define TOW0 128
#define TOW1 64

typedef __bf16 bf16x8 __attribute__((ext_vector_type(8)));
typedef float f32x4 __attribute__((ext_vector_type(4)));
typedef float f32x16 __attribute__((ext_vector_type(16)));
typedef long lx2 __attribute__((ext_vector_type(2)));
typedef int i32x4 __attribute__((ext_vector_type(4)));
typedef int i32x8 __attribute__((ext_vector_type(8)));

#define SCL 0x7F7F7F7F  // E8M0 1.0 in all 4 bytes

__device__ __forceinline__ void gload_lds16(const void* g, void* l) {
  __builtin_amdgcn_global_load_lds(
      (const __attribute__((address_space(1))) void*)g,
      (__attribute__((address_space(3))) void*)l, 16, 0, 0);
}

#define BAR() do { asm volatile("" ::: "memory"); __builtin_amdgcn_s_barrier(); asm volatile("" ::: "memory"); } while (0)
#define VM4() asm volatile("s_waitcnt vmcnt(4)" ::: "memory")
#define VM3() asm volatile("s_waitcnt vmcnt(3)" ::: "memory")

// old k-perm (16x16 frag layout) — used for WgT8 (gate B operand)
__device__ __forceinline__ int permk(int k6) {
  return (k6 & 7) + (((k6 >> 3) & 3) << 4) + (((k6 >> 5) & 1) << 3);
}

// fp8 MX content layout (proven rounds 11-14)
__device__ __forceinline__ size_t mxpos(int row, int kabs, int K) {
  int kt = kabs >> 6, kk = kabs & 63;
  int reg = row & ~63, ro = row & 63;
  int sub = ro >> 5, rr = ro & 31, r = rr & 15;
  int u = ((kk >> 5) << 1) | ((rr >> 4) & 1);
  int p = (kk >> 4) & 1;
  int g = (sub << 1) | p;
  return (size_t)(reg + g * 16 + r) * K + kt * 64 + u * 16 + (kk & 15);
}

// fp4 content layout: K-tile = 128 elements = 64 B/row; piece j = k>>6 in the
// g-bit (same role as fp8's p); byte holds k-pair (lo nibble = even k).
// Returns byte index (stride in bytes); k must address the pair's even k.
__device__ __forceinline__ size_t mx4pos(int row, int k, int stride) {
  int kt = k >> 7, kr = k & 127;
  int j = kr >> 6, kk = kr & 63;
  int hb = (kk >> 5) & 1, b = (kk & 31) >> 1;
  int reg = row & ~63, ro = row & 63;
  int sub = ro >> 5, rr = ro & 31, rbit = (rr >> 4) & 1, rq = rr & 15;
  int g = (sub << 1) | j;
  int u = (hb << 1) | rbit;
  return (size_t)(reg + g * 16 + rq) * stride + kt * 64 + u * 16 + b;
}

// ---------------- f32 -> OCP e4m3fn software fallback
__device__ __forceinline__ unsigned char f2e4m3_sw(float x) {
  unsigned su = (__float_as_uint(x) >> 24) & 0x80u;
  float ax = fabsf(x);
  if (!(ax < 448.f)) return (unsigned char)(su | 0x7E);
  if (ax == 0.f) return (unsigned char)su;
  int e;
  float m = frexpf(ax, &e);
  int E = e - 1;
  if (E < -6) {
    int mi = (int)rintf(ldexpf(ax, 9));
    if (mi >= 8) return (unsigned char)(su | 0x08);
    return (unsigned char)(su | mi);
  }
  int mi = (int)rintf(ldexpf(m, 4));
  if (mi == 16) { mi = 8; E += 1; if (E > 8) return (unsigned char)(su | 0x7E); }
  return (unsigned char)(su | ((E + 7) << 3) | (mi - 8));
}

#if __has_builtin(__builtin_amdgcn_cvt_pk_fp8_f32)
#define HAS_HW_FP8 1
__device__ __forceinline__ int cvtpk8_lo(float a, float b, int old) {
  return __builtin_amdgcn_cvt_pk_fp8_f32(a, b, old, false);
}
__device__ __forceinline__ int cvtpk8_hi(float a, float b, int old) {
  return __builtin_amdgcn_cvt_pk_fp8_f32(a, b, old, true);
}
__device__ __forceinline__ unsigned char f2e4m3(float x) {
  return (unsigned char)(__builtin_amdgcn_cvt_pk_fp8_f32(x, x, 0, false) & 0xFF);
}
#else
#define HAS_HW_FP8 0
__device__ __forceinline__ unsigned char f2e4m3(float x) { return f2e4m3_sw(x); }
#endif

__device__ __forceinline__ unsigned pk4_fp8(float a, float b, float c, float d) {
#if HAS_HW_FP8
  int v = cvtpk8_lo(a, b, 0);
  v = cvtpk8_hi(c, d, v);
  return (unsigned)v;
#else
  return (unsigned)f2e4m3_sw(a) | ((unsigned)f2e4m3_sw(b) << 8) |
         ((unsigned)f2e4m3_sw(c) << 16) | ((unsigned)f2e4m3_sw(d) << 24);
#endif
}

// f32 -> e2m1 nibble (levels 0,0.5,1,1.5,2,3,4,6; nearest)
__device__ __forceinline__ unsigned f2e2m1(float x) {
  unsigned s = x < 0.f ? 8u : 0u;
  float a = fabsf(x);
  unsigned m;
  if (a < 0.25f) m = 0;
  else if (a < 0.75f) m = 1;
  else if (a < 1.25f) m = 2;
  else if (a < 1.75f) m = 3;
  else if (a < 2.5f)  m = 4;
  else if (a < 3.5f)  m = 5;
  else if (a < 5.f)   m = 6;
  else m = 7;
  return s | m;
}

// ---------------- weight prep ----------------
// We1 -> fp4 x64 MX4 layout; We2 -> fp8 x16 MX; Wg -> fp8 x16 k-perm
__device__ __forceinline__ void trans_tile_fp8mx(
    const float* __restrict__ inp, unsigned char* __restrict__ outp,
    int R, int C, int cx, int ry, float (*tile)[33])
{
  int c0 = cx * 32, r0 = ry * 32;
  int tx = threadIdx.x & 31, ty = threadIdx.x >> 5;
#pragma unroll
  for (int i = 0; i < 32; i += 8)
    tile[ty + i][tx] = inp[(size_t)(r0 + ty + i) * C + c0 + tx];
  __syncthreads();
  int ki = r0 + tx;
#pragma unroll
  for (int i = 0; i < 32; i += 8)
    outp[mxpos(c0 + ty + i, ki, R)] = f2e4m3(tile[tx][ty + i] * 16.f);
}

__device__ __forceinline__ void trans_tile_fp4(
    const float* __restrict__ inp, unsigned char* __restrict__ outp,
    int C, int cx, int ry, float (*tile)[33])
{
  // tile[a][b] = inp element (k = r0+a, outrow = c0+b); out stride KS4.
  int c0 = cx * 32, r0 = ry * 32;
  int tx = threadIdx.x & 31, ty = threadIdx.x >> 5;
#pragma unroll
  for (int i = 0; i < 32; i += 8)
    tile[ty + i][tx] = inp[(size_t)(r0 + ty + i) * C + c0 + tx];
  __syncthreads();
#pragma unroll
  for (int w = threadIdx.x; w < 512; w += 256) {
    int nl = w & 31, bp = w >> 5;   // out-row offset, k-pair index
    unsigned by = f2e2m1(tile[2 * bp][nl] * 64.f) |
                  (f2e2m1(tile[2 * bp + 1][nl] * 64.f) << 4);
    outp[mx4pos(c0 + nl, r0 + 2 * bp, KS4)] = (unsigned char)by;
  }
}

// We1 tiles: 6912 ; We2 tiles: 1024 ; Wg: 108 blocks
__global__ __launch_bounds__(256) void prep_weights(
    const float* __restrict__ We1, const float* __restrict__ We2,
    const float* __restrict__ Wg,
    unsigned char* __restrict__ We1T4, unsigned char* __restrict__ We2T8,
    unsigned char* __restrict__ WgT8)
{
  __shared__ float tile[32][33];
  int id = blockIdx.x;
  if (id < 6912) {
    int z = id / 864, r = id - z * 864;
    int cx = r & 15, ry = r >> 4;
    trans_tile_fp4(We1 + (size_t)z * D_DIM * BOT0, We1T4 + (size_t)z * BOT0 * KS4,
                   BOT0, cx, ry, tile);
  } else if (id < 7936) {
    int r2 = id - 6912;
    int z = r2 >> 7, r = r2 & 127;
    int cx = r & 7, ry = r >> 3;
    trans_tile_fp8mx(We2 + (size_t)z * BOT0 * BOT1, We2T8 + (size_t)z * BOT0 * BOT1,
                     BOT0, BOT1, cx, ry, tile);
  } else {
    int i = (id - 7936) * 256 + threadIdx.x; // over 16*1728
    int n = i / D_DIM, d = i - n * D_DIM;
    int t = n >> 3, e2 = n & 7;
    int pd = (d & ~63) + permk(d & 63);
    WgT8[(size_t)n * D_DIM + pd] =
        f2e4m3(Wg[((size_t)t * D_DIM + d) * E_EXP + e2] * 16.f);
  }
}

// ---------------- embedding gather + numeric linear -> emb8 (fp8 MX, for gate)
//                  + emb4 (fp4 x32, MX4 layout, for GEMM1)
__global__ __launch_bounds__(256) void embed_convert(
    const int* __restrict__ cat, const float* __restrict__ numx,
    const int* __restrict__ offsets, const float* __restrict__ W_emb,
    const float* __restrict__ Wn, const float* __restrict__ bnum,
    unsigned char* __restrict__ emb8, unsigned char* __restrict__ emb4)
{
  int W = blockIdx.x * 256 + threadIdx.x;
  int prow = W / 108, ucol = W - prow * 108;
  int f = ucol >> 2, u = ucol & 3;
  int reg = prow & ~63, po = prow & 63;
  int g = po >> 4, r = po & 15;
  int sub = g >> 1, p = g & 1;
  int h = u >> 1, rbit = u & 1;
  int b = reg + sub * 32 + rbit * 16 + r;
  int kk = h * 32 + p * 16;
  float vals[16];
  if (f < F_CAT) {
    int row = cat[(size_t)b * F_CAT + f] + offsets[f];
    const float4* src = reinterpret_cast<const float4*>(&W_emb[(size_t)row * ED + kk]);
#pragma unroll
    for (int q = 0; q < 4; ++q) {
      float4 v = src[q];
      vals[q * 4 + 0] = v.x; vals[q * 4 + 1] = v.y;
      vals[q * 4 + 2] = v.z; vals[q * 4 + 3] = v.w;
    }
  } else {
#pragma unroll
    for (int j = 0; j < 16; ++j) vals[j] = bnum[kk + j];
    for (int n = 0; n < NUM_N; ++n) {
      float x = numx[(size_t)b * NUM_N + n];
      const float* wr = &Wn[n * ED + kk];
#pragma unroll
      for (int j = 0; j < 16; ++j) vals[j] = fmaf(x, wr[j], vals[j]);
    }
  }
  uint4 o;
  o.x = pk4_fp8(vals[0] * 16.f, vals[1] * 16.f, vals[2] * 16.f, vals[3] * 16.f);
  o.y = pk4_fp8(vals[4] * 16.f, vals[5] * 16.f, vals[6] * 16.f, vals[7] * 16.f);
  o.z = pk4_fp8(vals[8] * 16.f, vals[9] * 16.f, vals[10] * 16.f, vals[11] * 16.f);
  o.w = pk4_fp8(vals[12] * 16.f, vals[13] * 16.f, vals[14] * 16.f, vals[15] * 16.f);
  *reinterpret_cast<uint4*>(&emb8[(size_t)prow * D_DIM + f * 64 + u * 16]) = o;

  // fp4 (x32): 16 k -> 8 bytes at MX4 position
  unsigned long long pk8 = 0;
#pragma unroll
  for (int c = 0; c < 8; ++c) {
    unsigned by = f2e2m1(vals[2 * c] * 32.f) |
                  (f2e2m1(vals[2 * c + 1] * 32.f) << 4);
    pk8 |= (unsigned long long)by << (8 * c);
  }
  int k0g = f * 64 + kk;
  *reinterpret_cast<unsigned long long*>(&emb4[mx4pos(b, k0g, KS4)]) = pk8;
}

// ---------------- gate GEMM (fp8, proven round-11) + fused softmax
__global__ __launch_bounds__(256) void gate_mfma(
    const unsigned char* __restrict__ emb8, const unsigned char* __restrict__ WgT8,
    const float* __restrict__ bg, float* __restrict__ gate)
{
  int wid = threadIdx.x >> 6, lane = threadIdx.x & 63;
  int l15 = lane & 15, lh = lane >> 4;
  int r0 = (blockIdx.x * 4 + wid) * 16;
  f32x4 acc = {};
  int b = r0 + l15;
  int reg = b & ~63, ro = b & 63;
  int sub = ro >> 5, rr = ro & 31;
  int rbit = (rr >> 4) & 1, rq = rr & 15;
  int pgh = lh >> 1;
  int prow = reg + (((sub << 1) | pgh) << 4) + rq;
  const unsigned char* arow = emb8 + (size_t)prow * D_DIM + rbit * 16 + (lh & 1) * 8;
  const unsigned char* brow = WgT8 + (size_t)l15 * D_DIM + lh * 16;
#pragma unroll 3
  for (int k = 0; k < D_DIM; k += 64) {
    long a0 = *reinterpret_cast<const long*>(arow + k);
    long a1 = *reinterpret_cast<const long*>(arow + k + 32);
    lx2 bv = *reinterpret_cast<const lx2*>(brow + k);
    acc = __builtin_amdgcn_mfma_f32_16x16x32_fp8_fp8(a0, bv[0], acc, 0, 0, 0);
    acc = __builtin_amdgcn_mfma_f32_16x16x32_fp8_fp8(a1, bv[1], acc, 0, 0, 0);
  }
  int t = l15 >> 3, e = l15 & 7;
  float bv = bg[t * E_EXP + e];
#pragma unroll
  for (int r = 0; r < 4; ++r) {
    float lg = acc[r] * (1.f / 256.f) + bv;
    float m = lg;
    m = fmaxf(m, __shfl_xor(m, 1));
    m = fmaxf(m, __shfl_xor(m, 2));
    m = fmaxf(m, __shfl_xor(m, 4));
    float ex = expf(lg - m);
    float s = ex;
    s += __shfl_xor(s, 1);
    s += __shfl_xor(s, 2);
    s += __shfl_xor(s, 4);
    int row = r0 + lh * 4 + r;
    gate[((size_t)t * B_SZ + row) * E_EXP + e] = ex / s;
  }
}

// load 32 B (two b128 at +1024 = pieces j0,j1) into v8i32
__device__ __forceinline__ i32x8 ld32(const char* base, int off) {
  i32x4 a = *reinterpret_cast<const i32x4*>(base + off);
  i32x4 b = *reinterpret_cast<const i32x4*>(base + off + 1024);
  i32x8 r;
  r[0] = a[0]; r[1] = a[1]; r[2] = a[2]; r[3] = a[3];
  r[4] = b[0]; r[5] = b[1]; r[6] = b[2]; r[7] = b[3];
  return r;
}

// move piece1 into the low 4 regs (HW reads [0:3] for fp4; upper ignored)
__device__ __forceinline__ i32x8 hi8(i32x8 v) {
  i32x8 r = v;
  r[0] = v[4]; r[1] = v[5]; r[2] = v[6]; r[3] = v[7];
  return r;
}

#define MXMFMA(va, vb, c) \
  __builtin_amdgcn_mfma_scale_f32_32x32x64_f8f6f4(va, vb, c, 0, 0, 0, SCL, 0, SCL)
#define MX4MFMA(va, vb, c) \
  __builtin_amdgcn_mfma_scale_f32_32x32x64_f8f6f4(va, vb, c, 4, 4, 0, SCL, 0, SCL)

// =========================================================================
// FP4 2-phase 256x256 GEMM (GEMM1): K-tile = 128 elements = 64 B/row.
// Staging/LDS/swizzle/read pattern BYTE-IDENTICAL to the proven fp8 MX
// kernel; content is mx4pos fp4. 13 full tiles + j0-only tail (K=64).
// Operands: A x32, B x64 -> descale 1/2048. Output H8 fp8 x16 MX (proven).
// =========================================================================
__global__ __launch_bounds__(512, 2) void gemm_mx4(
    const unsigned char* __restrict__ A4, size_t strideAe,
    const unsigned char* __restrict__ BT4,
    const float* __restrict__ bias,
    unsigned char* __restrict__ C8,
    int M, int N, int K)
{
  extern __shared__ char smem[];
  int e = blockIdx.z;
  const unsigned char* Ap = A4 + strideAe * (size_t)e;
  const unsigned char* Bp = BT4 + (size_t)e * N * KS4;
  const float* bp = bias + (size_t)e * N;
  unsigned char* Cp8 = C8 + (size_t)e * M * N;
  int bm0 = blockIdx.x * 256, bn0 = blockIdx.y * 256;

  int tid = threadIdx.x;
  int wid = tid >> 6, lane = tid & 63;
  int l15 = lane & 15, lh = lane >> 4;
  int l31 = lane & 31, hl = lane >> 5;
  int wrow = (wid >> 2) * 128, wcol = (wid & 3) * 64;

  int slotc = (lh ^ (((l15 >> 3) & 1) << 1)) << 4;
  const char* rdA = smem + (wrow + l15) * 64 + slotc;
  const char* rdB = smem + 49152 + (wcol + l15) * 64 + slotc;
  char* stA = smem + (wid << 10);
  char* stB = smem + 49152 + (wid << 10);

  int srow = tid >> 2;
  int ssw = (tid & 3) ^ (((srow >> 3) & 1) << 1);
  const unsigned char* gA0 = Ap + (size_t)(bm0 + srow) * KS4 + ssw * 16;
  const unsigned char* gA1 = Ap + (size_t)(bm0 + 128 + srow) * KS4 + ssw * 16;
  const unsigned char* gB0 = Bp + (size_t)(bn0 + srow) * KS4 + ssw * 16;
  const unsigned char* gB1 = Bp + (size_t)(bn0 + 128 + srow) * KS4 + ssw * 16;

  auto STAGE = [&](int koff, int buf) {
    gload_lds16(gA0 + koff, stA + buf * 16384);
    gload_lds16(gA1 + koff, stA + buf * 16384 + 8192);
    gload_lds16(gB0 + koff, stB + buf * 16384);
    gload_lds16(gB1 + koff, stB + buf * 16384 + 8192);
  };

  f32x16 acc[4][2] = {};
  int NTf = K >> 7;   // 13 full 128-k tiles; tail of 64 k afterwards

  STAGE(0, 0);
  STAGE(64, 1);
  VM4();
  BAR();

  int bufc = 0, koff = 128;
  for (int T = 0; T < NTf; ++T) {
    const char* As = rdA + bufc * 16384;
    const char* Bs = rdB + bufc * 16384;
    int sb = bufc >= 1 ? bufc - 1 : 2;
    i32x8 va0, va1, vb0, vb1;

    // ---- p0: chunks mi0,mi1 (both j) + B chunks; stage tile T+2
    va0 = ld32(As, 0);
    va1 = ld32(As, 2048);
    vb0 = ld32(Bs, 0);
    vb1 = ld32(Bs, 2048);
    STAGE(koff, sb);
    BAR();
    __builtin_amdgcn_s_setprio(1);
    acc[0][0] = MX4MFMA(va0, vb0, acc[0][0]);
    acc[0][0] = MX4MFMA(hi8(va0), hi8(vb0), acc[0][0]);
    acc[0][1] = MX4MFMA(va0, vb1, acc[0][1]);
    acc[0][1] = MX4MFMA(hi8(va0), hi8(vb1), acc[0][1]);
    acc[1][0] = MX4MFMA(va1, vb0, acc[1][0]);
    acc[1][0] = MX4MFMA(hi8(va1), hi8(vb0), acc[1][0]);
    acc[1][1] = MX4MFMA(va1, vb1, acc[1][1]);
    acc[1][1] = MX4MFMA(hi8(va1), hi8(vb1), acc[1][1]);
    __builtin_amdgcn_s_setprio(0);
    BAR();

    // ---- p1: chunks mi2,mi3; VM4 certifies T+1
    va0 = ld32(As, 4096);
    va1 = ld32(As, 6144);
    BAR();
    __builtin_amdgcn_s_setprio(1);
    acc[2][0] = MX4MFMA(va0, vb0, acc[2][0]);
    acc[2][0] = MX4MFMA(hi8(va0), hi8(vb0), acc[2][0]);
    acc[2][1] = MX4MFMA(va0, vb1, acc[2][1]);
    acc[2][1] = MX4MFMA(hi8(va0), hi8(vb1), acc[2][1]);
    acc[3][0] = MX4MFMA(va1, vb0, acc[3][0]);
    acc[3][0] = MX4MFMA(hi8(va1), hi8(vb0), acc[3][0]);
    acc[3][1] = MX4MFMA(va1, vb1, acc[3][1]);
    acc[3][1] = MX4MFMA(hi8(va1), hi8(vb1), acc[3][1]);
    __builtin_amdgcn_s_setprio(0);
    VM4();
    BAR();

    koff += 64;
    bufc = bufc == 2 ? 0 : bufc + 1;
  }

  // ---- tail tile (k 1664..1727): piece j0 only; hi pieces are garbage
  {
    const char* As = rdA + bufc * 16384;
    const char* Bs = rdB + bufc * 16384;
    i32x8 vb0 = ld32(Bs, 0), vb1 = ld32(Bs, 2048);
#pragma unroll
    for (int mi = 0; mi < 4; ++mi) {
      i32x8 va = ld32(As, mi * 2048);
      acc[mi][0] = MX4MFMA(va, vb0, acc[mi][0]);
      acc[mi][1] = MX4MFMA(va, vb1, acc[mi][1]);
    }
  }

  // epilogue: drain; descale 1/2048 + bias + relu; fp8 x16 MX H8 via HW
  // cvt_pk into cs8 [256][256], then coalesced 16 B stores (proven).
  asm volatile("s_waitcnt vmcnt(0)" ::: "memory");
  BAR();
  unsigned char* cs8 = (unsigned char*)smem;
#pragma unroll
  for (int mi = 0; mi < 4; ++mi) {
#pragma unroll
    for (int nj = 0; nj < 2; ++nj) {
      int colT = wcol + nj * 32 + l31;
      float bv = bp[bn0 + colT];
      int kk = colT & 63;
      int ktrel = colT >> 6;
      int p = (kk >> 4) & 1;
      int ubase = (kk >> 5) << 1;
      int b4 = kk & 15;
      f32x16 a = acc[mi][nj];
      int rowBase = wrow + mi * 32 + (hl << 2);
#pragma unroll
      for (int rg = 0; rg < 16; rg += 2) {
        int row0 = rowBase + (rg & 3) + ((rg >> 2) << 3);
        float v0 = fmaxf(a[rg] * (1.f / 2048.f) + bv, 0.f) * 16.f;
        float v1 = fmaxf(a[rg + 1] * (1.f / 2048.f) + bv, 0.f) * 16.f;
#if HAS_HW_FP8
        int pk = cvtpk8_lo(v0, v1, 0);
#else
        int pk = (int)f2e4m3_sw(v0) | ((int)f2e4m3_sw(v1) << 8);
#endif
#pragma unroll
        for (int q = 0; q < 2; ++q) {
          int rowT = row0 + q;
          int regrel = rowT & ~63, ro = rowT & 63;
          int sub = ro >> 5, rr2 = ro & 31, r = rr2 & 15;
          int u = ubase | ((rr2 >> 4) & 1);
          int g = (sub << 1) | p;
          cs8[(regrel + g * 16 + r) * 256 + ktrel * 64 + u * 16 + b4] =
              (unsigned char)((pk >> (q * 8)) & 0xFF);
        }
      }
    }
  }
  BAR();
  {
    int rr = tid >> 4, c16 = (tid & 15) * 16;
#pragma unroll
    for (int p2 = 0; p2 < 8; ++p2) {
      int row = p2 * 32 + rr;
      *reinterpret_cast<uint4*>(&Cp8[(size_t)(bm0 + row) * N + bn0 + c16]) =
          *reinterpret_cast<const uint4*>(&cs8[(size_t)row * 256 + c16]);
    }
  }
}

// =========================================================================
// MX-fp8 BM=128 x BN=256 GEMM (GEMM2) — round-14 proven (H8 -> fea bf16).
// =========================================================================
__global__ __launch_bounds__(512, 2) void gemm_mx128(
    const unsigned char* __restrict__ A8, size_t strideAe,
    const unsigned char* __restrict__ BT8,
    const float* __restrict__ bias,
    __hip_bfloat16* __restrict__ C,
    int M, int N, int K)
{
  extern __shared__ char smem[];
  int e = blockIdx.z;
  const unsigned char* Ap = A8 + strideAe * (size_t)e;
  const unsigned char* Bp = BT8 + (size_t)e * N * K;
  const float* bp = bias + (size_t)e * N;
  __hip_bfloat16* Cp = C + (size_t)e * M * N;
  int bm0 = blockIdx.x * 128;

  int tid = threadIdx.x;
  int wid = tid >> 6, lane = tid & 63;
  int l15 = lane & 15, lh = lane >> 4;
  int l31 = lane & 31, hl = lane >> 5;
  int wrow = (wid >> 2) * 64, wcol = (wid & 3) * 64;

  int slotc = (lh ^ (((l15 >> 3) & 1) << 1)) << 4;
  const char* rdA = smem + (wrow + l15) * 64 + slotc;
  const char* rdB = smem + 24576 + (wcol + l15) * 64 + slotc;
  char* stA = smem + (wid << 10);
  char* stB = smem + 24576 + (wid << 10);

  int srow = tid >> 2;
  int ssw = (tid & 3) ^ (((srow >> 3) & 1) << 1);
  const unsigned char* gA0 = Ap + (size_t)(bm0 + srow) * K + ssw * 16;
  const unsigned char* gB0 = Bp + (size_t)srow * K + ssw * 16;
  const unsigned char* gB1 = Bp + (size_t)(128 + srow) * K + ssw * 16;

  auto STAGE = [&](int koff, int buf) {
    gload_lds16(gA0 + koff, stA + buf * 8192);
    gload_lds16(gB0 + koff, stB + buf * 16384);
    gload_lds16(gB1 + koff, stB + buf * 16384 + 8192);
  };

  f32x16 acc[2][2] = {};
  int NT = K >> 6;  // 8

  STAGE(0, 0);
  STAGE(64, 1);
  VM3();
  BAR();

  int bufc = 0, koff = 128;
  for (int T = 0; T < NT; ++T) {
    const char* As = rdA + bufc * 8192;
    const char* Bs = rdB + bufc * 16384;
    int sb = bufc >= 1 ? bufc - 1 : 2;
    i32x8 va, vb0, vb1;

    va = ld32(As, 0);
    vb0 = ld32(Bs, 0);
    vb1 = ld32(Bs, 2048);
    STAGE(koff, sb);
    BAR();
    __builtin_amdgcn_s_setprio(1);
    acc[0][0] = MXMFMA(va, vb0, acc[0][0]);
    acc[0][1] = MXMFMA(va, vb1, acc[0][1]);
    __builtin_amdgcn_s_setprio(0);
    BAR();

    va = ld32(As, 2048);
    BAR();
    __builtin_amdgcn_s_setprio(1);
    acc[1][0] = MXMFMA(va, vb0, acc[1][0]);
    acc[1][1] = MXMFMA(va, vb1, acc[1][1]);
    __builtin_amdgcn_s_setprio(0);
    VM3();
    BAR();

    koff += 64;
    bufc = bufc == 2 ? 0 : bufc + 1;
  }

  asm volatile("s_waitcnt vmcnt(0)" ::: "memory");
  BAR();
  __hip_bfloat16* cs = (__hip_bfloat16*)smem;
#pragma unroll
  for (int mi = 0; mi < 2; ++mi) {
#pragma unroll
    for (int nj = 0; nj < 2; ++nj) {
      int colT = wcol + nj * 32 + l31;
      float bv = bp[colT];
      f32x16 a = acc[mi][nj];
#pragma unroll
      for (int rg = 0; rg < 16; ++rg) {
        int rowT = wrow + mi * 32 + (rg & 3) + ((rg >> 2) << 3) + (hl << 2);
        float v = a[rg] * (1.f / 256.f) + bv;
        cs[(size_t)rowT * 256 + colT] = __float2bfloat16(fmaxf(v, 0.f));
      }
    }
  }
  BAR();
  {
    int rr = tid >> 5, c8 = (tid & 31) * 8;
#pragma unroll
    for (int p2 = 0; p2 < 8; ++p2) {
      int row = p2 * 16 + rr;
      *reinterpret_cast<uint4*>(&Cp[(size_t)(bm0 + row) * N + c8]) =
          *reinterpret_cast<const uint4*>(&cs[(size_t)row * 256 + c8]);
    }
  }
}

// ---------------- gate-combine + tower MLPs + sigmoid (round-14 proven)
#define TB 16
__global__ __launch_bounds__(256) void combine_tower(
    const float* __restrict__ gate, const __hip_bfloat16* __restrict__ fea,
    const float* __restrict__ Wt1, const float* __restrict__ bt1,
    const float* __restrict__ Wt2, const float* __restrict__ bt2,
    const float* __restrict__ Wt3, const float* __restrict__ bt3,
    float* __restrict__ out)
{
  int t = blockIdx.y;
  int b0 = blockIdx.x * TB;
  int tid = threadIdx.x;
  __shared__ float gs[TB][E_EXP];
  __shared__ float tf[TB][BOT1];
  __shared__ float h1[TB][TOW0];
  __shared__ float h2[TB][TOW1];
  if (tid < TB * E_EXP) {
    int bl = tid >> 3, e = tid & 7;
    gs[bl][e] = gate[((size_t)t * B_SZ + b0 + bl) * E_EXP + e];
  }
  __syncthreads();
  for (int i = tid; i < TB * BOT1; i += 256) {
    int bl = i >> 8, o = i & 255;
    float s = 0.f;
#pragma unroll
    for (int e = 0; e < E_EXP; ++e)
      s = fmaf(gs[bl][e], __bfloat162float(fea[((size_t)e * B_SZ + b0 + bl) * BOT1 + o]), s);
    tf[bl][o] = s;
  }
  __syncthreads();
  {
    int h = tid & 127, half = tid >> 7;
    float a[8] = {0, 0, 0, 0, 0, 0, 0, 0};
    for (int d = 0; d < BOT1; ++d) {
      float w = Wt1[((size_t)t * BOT1 + d) * TOW0 + h];
#pragma unroll
      for (int q = 0; q < 8; ++q) a[q] = fmaf(w, tf[half * 8 + q][d], a[q]);
    }
    float bv = bt1[t * TOW0 + h];
#pragma unroll
    for (int q = 0; q < 8; ++q) h1[half * 8 + q][h] = fmaxf(a[q] + bv, 0.f);
  }
  __syncthreads();
  {
    int h = tid & 63, qt = tid >> 6;
    float a[4] = {0, 0, 0, 0};
    for (int d = 0; d < TOW0; ++d) {
      float w = Wt2[((size_t)t * TOW0 + d) * TOW1 + h];
#pragma unroll
      for (int q = 0; q < 4; ++q) a[q] = fmaf(w, h1[qt * 4 + q][d], a[q]);
    }
    float bv = bt2[t * TOW1 + h];
#pragma unroll
    for (int q = 0; q < 4; ++q) h2[qt * 4 + q][h] = fmaxf(a[q] + bv, 0.f);
  }
  __syncthreads();
  {
    int l16 = tid & 15, bl = tid >> 4;
    float p = 0.f;
#pragma unroll
    for (int d = l16; d < TOW1; d += 16) p = fmaf(h2[bl][d], Wt3[t * TOW1 + d], p);
#pragma unroll
    for (int o = 8; o; o >>= 1) p += __shfl_down(p, o, 16);
    if (l16 == 0) {
      float lg = p + bt3[t];
      out[(size_t)t * B_SZ + b0 + bl] = 1.f / (1.f + expf(-lg));
    }
  }
}

extern "C" void kernel_launch(void* const* d_in, const int* in_sizes, int n_in,
                              void* d_out, int out_size, void* d_ws, size_t ws_size,
                              hipStream_t stream) {
  const int* cat = (const int*)d_in[0];
  const float* numx = (const float*)d_in[1];
  const int* offsets = (const int*)d_in[2];
  const float* W_emb = (const float*)d_in[3];
  const float* Wn = (const float*)d_in[4];
  const float* bnv = (const float*)d_in[5];
  const float* We1 = (const float*)d_in[6];
  const float* be1 = (const float*)d_in[7];
  const float* We2 = (const float*)d_in[8];
  const float* be2 = (const float*)d_in[9];
  const float* Wg = (const float*)d_in[10];
  const float* bg = (const float*)d_in[11];
  const float* Wt1 = (const float*)d_in[12];
  const float* bt1 = (const float*)d_in[13];
  const float* Wt2 = (const float*)d_in[14];
  const float* bt2 = (const float*)d_in[15];
  const float* Wt3 = (const float*)d_in[16];
  const float* bt3 = (const float*)d_in[17];
  float* out = (float*)d_out;

  char* ws = (char*)d_ws;
  size_t off = 0;
  auto alloc = [&](size_t bytes) {
    char* p = ws + off;
    off += (bytes + 255) & ~(size_t)255;
    return p;
  };
  unsigned char*  emb8  = (unsigned char*)alloc((size_t)B_SZ * D_DIM);
  unsigned char*  emb4  = (unsigned char*)alloc((size_t)B_SZ * KS4);
  unsigned char*  We1T4 = (unsigned char*)alloc((size_t)E_EXP * BOT0 * KS4);
  unsigned char*  We2T8 = (unsigned char*)alloc((size_t)E_EXP * BOT1 * BOT0);
  unsigned char*  H8    = (unsigned char*)alloc((size_t)E_EXP * B_SZ * BOT0);
  __hip_bfloat16* fea   = (__hip_bfloat16*)alloc((size_t)E_EXP * B_SZ * BOT1 * 2);
  float* gate = (float*)alloc((size_t)T_TASK * B_SZ * E_EXP * 4);
  unsigned char*  WgT8  = (unsigned char*)alloc((size_t)T_TASK * E_EXP * D_DIM);
  (void)alloc(8192); // slack: gemm tail prefetch overruns past last row

  hipFuncSetAttribute((const void*)gemm_mx4,
                      hipFuncAttributeMaxDynamicSharedMemorySize, 98304);
  hipFuncSetAttribute((const void*)gemm_mx128,
                      hipFuncAttributeMaxDynamicSharedMemorySize, 73728);

  // 1. weight prep (We1T4 fp4 x64 MX4, We2T8 fp8 x16 MX, WgT8 fp8 k-perm)
  prep_weights<<<dim3(8044), 256, 0, stream>>>(We1, We2, Wg, We1T4, We2T8, WgT8);

  // 2. embedding gather + numeric linear -> emb8 (gate) + emb4 (GEMM1)
  embed_convert<<<dim3(B_SZ * 108 / 256), 256, 0, stream>>>(
      cat, numx, offsets, W_emb, Wn, bnv, emb8, emb4);

  // 3. gate GEMM (fp8 direct-from-global) + softmax
  gate_mfma<<<dim3(B_SZ / 64), 256, 0, stream>>>(emb8, WgT8, bg, gate);

  // 4. expert layer 1 (MX-fp4): (4096x1728)x(1728x512) x8 -> H8 fp8-MX
  gemm_mx4<<<dim3(B_SZ / 256, BOT0 / 256, E_EXP), 512, 98304, stream>>>(
      emb4, (size_t)0, We1T4, be1, H8, B_SZ, BOT0, D_DIM);

  // 5. expert layer 2 (MX-fp8): (4096x512)x(512x256) x8 -> fea bf16
  gemm_mx128<<<dim3(B_SZ / 128, 1, E_EXP), 512, 73728, stream>>>(
      H8, (size_t)B_SZ * BOT0, We2T8, be2, fea, B_SZ, BOT1, BOT0);

  // 6. gated combine + towers + sigmoid
  combine_tower<<<dim3(B_SZ / TB, T_TASK), 256, 0, stream>>>(
      gate, fea, Wt1, bt1, Wt2, bt2, Wt3, bt3, out);
}